// Round 1
// baseline (940.025 us; speedup 1.0000x reference)
//
#include <hip/hip_runtime.h>

typedef unsigned int uint;
typedef short bf16x8 __attribute__((ext_vector_type(8)));
typedef float f32x4 __attribute__((ext_vector_type(4)));

// ---------- bf16 helpers (bit-level, RNE) ----------
__device__ __forceinline__ unsigned short f2b(float f) {
    uint u = __builtin_bit_cast(uint, f);
    u += 0x7fffu + ((u >> 16) & 1u);
    return (unsigned short)(u >> 16);
}
__device__ __forceinline__ float b2f(unsigned short h) {
    uint u = ((uint)h) << 16;
    return __builtin_bit_cast(float, u);
}

// ---------- fast tanh-gelu ----------
__device__ __forceinline__ float fast_gelu(float v) {
    float s  = v * v;
    float t2 = __builtin_fmaf(0.044715f * s, v, v);     // v + 0.044715 v^3
    float e  = __expf(-1.5957691216f * t2);             // exp(-2*0.79788456*t2)
    return v * __builtin_amdgcn_rcpf(1.0f + e);
}

// ---------- async global->LDS, 16B per lane (wave-uniform LDS base + lane*16) ----------
__device__ __forceinline__ void gl_lds16(const unsigned short* g, unsigned short* l) {
    __builtin_amdgcn_global_load_lds(
        reinterpret_cast<const __attribute__((address_space(1))) unsigned int*>(
            reinterpret_cast<uintptr_t>(g)),
        reinterpret_cast<__attribute__((address_space(3))) unsigned int*>(
            reinterpret_cast<uintptr_t>(l)),
        16, 0, 0);
}

// ---------- weight prep ----------
__global__ __launch_bounds__(256) void convert_bf16_kernel(const float* __restrict__ src,
                                                           unsigned short* __restrict__ dst, int n) {
    int idx = blockIdx.x * 256 + threadIdx.x;
    if (idx < n) dst[idx] = f2b(src[idx]);
}

// src is (K, N) row-major; dst is (N, K) row-major (i.e. B^T), bf16.
__global__ __launch_bounds__(256) void transpose_to_bf16_kernel(const float* __restrict__ src,
                                                                unsigned short* __restrict__ dst,
                                                                int K, int N) {
    long long idx = (long long)blockIdx.x * 256 + threadIdx.x;
    if (idx >= (long long)K * N) return;
    int k = (int)(idx / N);
    int n = (int)(idx % N);
    dst[(long long)n * K + k] = f2b(src[idx]);
}

// ---------- im2col: input (B,C,H,W) -> A (16384, 768) bf16, k = c*256+p*16+q ----------
__global__ __launch_bounds__(256) void im2col_kernel(const float* __restrict__ in,
                                                     unsigned short* __restrict__ out) {
    long long idx = (long long)blockIdx.x * 256 + threadIdx.x; // < 16384*768
    int k = (int)(idx % 768);
    int n = (int)(idx / 768);
    int b = n >> 10, t = n & 1023;
    int hp = t >> 5, wp = t & 31;
    int c = k >> 8, rm = k & 255;
    int p = rm >> 4, q = rm & 15;
    long long src = (((long long)(b * 3 + c) * 512) + hp * 16 + p) * 512 + wp * 16 + q;
    out[idx] = f2b(in[src]);
}

// ---------- LayerNorm + sinusoidal PE -> bf16 ----------
__global__ __launch_bounds__(256) void ln_pe_kernel(const float* __restrict__ xe,
                                                    const float* __restrict__ g,
                                                    const float* __restrict__ bb,
                                                    unsigned short* __restrict__ xb) {
    int row = blockIdx.x;            // 0..16383
    int pos = row & 1023;
    const float* xr = xe + (long long)row * 768;
    float v0 = xr[threadIdx.x];
    float v1 = xr[threadIdx.x + 256];
    float v2 = xr[threadIdx.x + 512];
    float s = v0 + v1 + v2;
    float sq = v0 * v0 + v1 * v1 + v2 * v2;
    for (int o = 32; o > 0; o >>= 1) {
        s  += __shfl_down(s, o, 64);
        sq += __shfl_down(sq, o, 64);
    }
    __shared__ float ps[4], pq[4];
    int w = threadIdx.x >> 6, lane = threadIdx.x & 63;
    if (lane == 0) { ps[w] = s; pq[w] = sq; }
    __syncthreads();
    float ts = ps[0] + ps[1] + ps[2] + ps[3];
    float tq = pq[0] + pq[1] + pq[2] + pq[3];
    float mean = ts * (1.0f / 768.0f);
    float var  = tq * (1.0f / 768.0f) - mean * mean;
    float inv  = rsqrtf(var + 1e-5f);
    #pragma unroll
    for (int dd = 0; dd < 3; dd++) {
        int d = threadIdx.x + dd * 256;
        float val = (dd == 0) ? v0 : (dd == 1) ? v1 : v2;
        float y = (val - mean) * inv * g[d] + bb[d];
        float freq = __expf(-(float)(d & ~1) * (9.210340371976184f / 768.0f));
        float ang = (float)pos * freq;
        y += (d & 1) ? cosf(ang) : sinf(ang);
        xb[(long long)row * 768 + d] = f2b(y);
    }
}

// ---------- 256x256 bf16 MFMA GEMM, BK=64, 8-phase counted-vmcnt pipeline ----------
// m201-template port (T2 XOR-swizzle + T3/T4 8-phase counted vmcnt + T5 setprio + T1 XCD swz).
// 512 threads = 8 waves (2 M-rows x 4 N-cols), per-wave 64x32 slice of each 128x128
// C-quadrant; quadrant snake order q00->q01->q11->q10 with A/B fragment register reuse,
// so each LDS half-slot's last ds_read is BARRIER-SEPARATED from its restaging:
//   p0 (A0,B0): stage B0(s+1)  [slot last read s-1.p3]
//   p1 (  ,B1): stage A0(s+2)  [slot last read this-group p0]
//   p2 (A1,  ): stage B1(s+2)  [slot last read p1]
//   p3 (  ,B0): stage A1(s+2)  [slot last read p2]
// One s_waitcnt vmcnt(6) per K-tile (3 half-tiles = 6 loads in flight), raw s_barrier
// (no counter drain). Tail groups stage clamped dummy loads into dead slots so the
// constant vmcnt(6) stays exact. LDS slot (row,c8) holds global (row, c8^(row&7));
// swizzle applied on the global-fetch side (global_load_lds dest must stay linear).
__global__ __launch_bounds__(512) void gemm256_kernel(const unsigned short* __restrict__ A,
                                                      const unsigned short* __restrict__ BT,
                                                      const float* __restrict__ bias,
                                                      const unsigned short* __restrict__ residB,
                                                      float* __restrict__ outF,
                                                      unsigned short* __restrict__ outB,
                                                      int M, int N, int K, int ldb,
                                                      int epi, int accumF) {
    __shared__ __align__(16) unsigned short As[2][256 * 64];   // 64 KB
    __shared__ __align__(16) unsigned short Bs[2][256 * 64];   // 64 KB

    // ---- XCD swizzle: id = 8*s + xcd; requires (M/256) % 8 == 0 (holds: 64)
    const int nX = N >> 8;                    // N/256
    int id = blockIdx.x;
    int xcd = id & 7;
    int sq_ = id >> 3;
    int bx = sq_ % nX;
    int by = (sq_ / nX) * 8 + xcd;
    const int m0 = by * 256, n0 = bx * 256;

    const int tid = threadIdx.x;
    const int w = tid >> 6, lane = tid & 63;
    const int wr = w >> 2, wc = w & 3;               // 2x4 wave grid
    const int quad = lane >> 4, l15 = lane & 15;
    const int swz = l15 & 7;                         // fragment-row swizzle key

    // ---- staging addressing: thread t -> LDS 16B-unit t (wave-uniform base + lane*16)
    const int row0 = tid >> 3;                       // 0..63
    const int c8   = tid & 7;
    const int gc8  = c8 ^ (row0 & 7);                // (row0+64)&7 == row0&7
    const unsigned short* Ag = A  + (long long)(m0 + row0) * K   + gc8 * 8;
    const unsigned short* Bg = BT + (long long)(n0 + row0) * ldb + gc8 * 8;
    unsigned short* Ad = &As[0][0] + row0 * 64 + c8 * 8;
    unsigned short* Bd = &Bs[0][0] + row0 * 64 + c8 * 8;
    const long long aK64 = (long long)64 * K,  aK128 = (long long)128 * K;
    const long long bL64 = (long long)64 * ldb, bL128 = (long long)128 * ldb;

#define STAGE_A(bsel, h, ks) { \
    const unsigned short* s_ = Ag + (h) * aK128 + (ks); \
    unsigned short* d_ = Ad + (bsel) * 16384 + (h) * 8192; \
    gl_lds16(s_, d_); gl_lds16(s_ + aK64, d_ + 4096); }
#define STAGE_B(bsel, h, ks) { \
    const unsigned short* s_ = Bg + (h) * bL128 + (ks); \
    unsigned short* d_ = Bd + (bsel) * 16384 + (h) * 8192; \
    gl_lds16(s_, d_); gl_lds16(s_ + bL64, d_ + 4096); }

    bf16x8 af[4][2], bfr[2][2];
    f32x4 acc[2][2][4][2] = {};

#define LOAD_AF(bsel, qm) { \
    const unsigned short* base_ = &As[bsel][((qm) * 128 + wr * 64 + l15) * 64]; \
    _Pragma("unroll") for (int mf_ = 0; mf_ < 4; mf_++) { \
      af[mf_][0] = *(const bf16x8*)(base_ + mf_ * 1024 + ((quad ^ swz) * 8)); \
      af[mf_][1] = *(const bf16x8*)(base_ + mf_ * 1024 + (((4 + quad) ^ swz) * 8)); \
    } }
#define LOAD_BF(bsel, qn) { \
    const unsigned short* base_ = &Bs[bsel][((qn) * 128 + wc * 32 + l15) * 64]; \
    _Pragma("unroll") for (int nf_ = 0; nf_ < 2; nf_++) { \
      bfr[nf_][0] = *(const bf16x8*)(base_ + nf_ * 1024 + ((quad ^ swz) * 8)); \
      bfr[nf_][1] = *(const bf16x8*)(base_ + nf_ * 1024 + (((4 + quad) ^ swz) * 8)); \
    } }
#define MFMA_Q(qm, qn) { \
    __builtin_amdgcn_sched_barrier(0); \
    __builtin_amdgcn_s_setprio(1); \
    _Pragma("unroll") for (int mf_ = 0; mf_ < 4; mf_++) \
    _Pragma("unroll") for (int nf_ = 0; nf_ < 2; nf_++) { \
      acc[qm][qn][mf_][nf_] = __builtin_amdgcn_mfma_f32_16x16x32_bf16(af[mf_][0], bfr[nf_][0], acc[qm][qn][mf_][nf_], 0, 0, 0); \
      acc[qm][qn][mf_][nf_] = __builtin_amdgcn_mfma_f32_16x16x32_bf16(af[mf_][1], bfr[nf_][1], acc[qm][qn][mf_][nf_], 0, 0, 0); \
    } \
    __builtin_amdgcn_s_setprio(0); \
    __builtin_amdgcn_sched_barrier(0); }
#define BAR() { asm volatile("" ::: "memory"); __builtin_amdgcn_s_barrier(); asm volatile("" ::: "memory"); }

    const int NT = K >> 6;                    // K-tiles (>= 2 for all call sites)

    // ---- prologue: K-tile 0 fully + {A0,B1,A1}(1); vmcnt(6) leaves newest 3 in flight
    STAGE_B(0, 0, 0);
    STAGE_A(0, 0, 0);
    STAGE_B(0, 1, 0);
    STAGE_A(0, 1, 0);
    STAGE_A(1, 0, 64);
    STAGE_B(1, 1, 64);
    STAGE_A(1, 1, 64);
    asm volatile("s_waitcnt vmcnt(6)" ::: "memory");
    BAR();

    for (int s = 0; s < NT; s++) {
        const int b = s & 1, bn = b ^ 1;
        const int ks1 = (s + 1 < NT) ? (s + 1) * 64 : 0;   // dummy loads land in dead slots
        const int ks2 = (s + 2 < NT) ? (s + 2) * 64 : 0;

        // phase 0: q00 (A0,B0) -- 12 ds_reads
        LOAD_AF(b, 0);
        LOAD_BF(b, 0);
        STAGE_B(bn, 0, ks1);                  // B0(s+1)
        asm volatile("s_waitcnt lgkmcnt(8)" ::: "memory");
        BAR();
        MFMA_Q(0, 0);
        BAR();
        // phase 1: q01 (A0 reused, B1) -- 4 ds_reads
        LOAD_BF(b, 1);
        STAGE_A(b, 0, ks2);                   // A0(s+2): slot's last read was p0
        BAR();
        MFMA_Q(0, 1);
        BAR();
        // phase 2: q11 (A1, B1 reused) -- 8 ds_reads
        LOAD_AF(b, 1);
        STAGE_B(b, 1, ks2);                   // B1(s+2): slot's last read was p1
        BAR();
        MFMA_Q(1, 1);
        BAR();
        // phase 3: q10 (A1 reused, B0 re-read) -- 4 ds_reads
        LOAD_BF(b, 0);
        STAGE_A(b, 1, ks2);                   // A1(s+2): slot's last read was p2
        BAR();
        MFMA_Q(1, 0);
        asm volatile("s_waitcnt vmcnt(6)" ::: "memory");   // once per K-tile, never 0
        BAR();
    }
    asm volatile("s_waitcnt vmcnt(0)" ::: "memory");       // drain tail dummy loads

    // ---- epilogue: v = acc (+ bias); epi==1 -> gelu; accumF -> +outF; residB -> +resid
    const int r0 = quad * 4;
    #pragma unroll
    for (int qm = 0; qm < 2; qm++)
    #pragma unroll
    for (int qn = 0; qn < 2; qn++)
    #pragma unroll
    for (int mf = 0; mf < 4; mf++)
    #pragma unroll
    for (int nf = 0; nf < 2; nf++) {
        int gn = n0 + qn * 128 + wc * 32 + nf * 16 + l15;
        float bv = bias ? bias[gn] : 0.0f;
        #pragma unroll
        for (int r = 0; r < 4; r++) {
            int gm = m0 + qm * 128 + wr * 64 + mf * 16 + r0 + r;
            float v = acc[qm][qn][mf][nf][r] + bv;
            if (epi == 1) v = fast_gelu(v);
            long long off = (long long)gm * N + gn;
            if (accumF) v += outF[off];
            if (residB) v += b2f(residB[off]);
            if (outF) outF[off] = v;
            if (outB) outB[off] = f2b(v);
        }
    }
#undef STAGE_A
#undef STAGE_B
#undef LOAD_AF
#undef LOAD_BF
#undef MFMA_Q
#undef BAR
}

// ---------- windowed attention: one block per (b, window, head), 52 KB LDS ----------
__global__ __launch_bounds__(256) void attn_kernel(const unsigned short* __restrict__ qkv,
                                                   unsigned short* __restrict__ o) {
    __shared__ float qs[64 * 65], ks[64 * 65], vs[64 * 65];  // qs reused for probs
    __shared__ float pmax[4 * 64], psum[4 * 64];
    int blk = blockIdx.x;                 // b*16*12 + w*12 + h
    int h = blk % 12;
    int bw = blk / 12;
    int wi = bw % 16, b = bw / 16;
    int rowBase = b * 1024 + wi * 64;
    int tid = threadIdx.x;

    int lr = tid >> 2, c0 = (tid & 3) * 16;
    const unsigned short* src = qkv + (long long)(rowBase + lr) * 2304 + h * 64 + c0;
    #pragma unroll
    for (int j = 0; j < 16; j++) {
        qs[lr * 65 + c0 + j] = b2f(src[j]);
        ks[lr * 65 + c0 + j] = b2f(src[768 + j]);
        vs[lr * 65 + c0 + j] = b2f(src[1536 + j]);
    }
    __syncthreads();

    int r = tid & 63, cg = tid >> 6;
    float svals[16] = {};
    for (int kk = 0; kk < 64; kk++) {
        float qv = qs[r * 65 + kk];                    // per-lane, 2-way bank alias (free)
        #pragma unroll
        for (int j = 0; j < 16; j++)
            svals[j] += qv * ks[(cg * 16 + j) * 65 + kk];   // wave-uniform broadcast
    }
    float smax = -1e30f;
    #pragma unroll
    for (int j = 0; j < 16; j++) {
        svals[j] *= 0.125f;
        smax = fmaxf(smax, svals[j]);
    }
    pmax[cg * 64 + r] = smax;
    __syncthreads();   // all qs(Q) reads done; qs reusable as prob buffer
    float m = fmaxf(fmaxf(pmax[r], pmax[64 + r]), fmaxf(pmax[128 + r], pmax[192 + r]));
    float lsum = 0.0f;
    #pragma unroll
    for (int j = 0; j < 16; j++) {
        float e = __expf(svals[j] - m);
        qs[r * 65 + cg * 16 + j] = e;
        lsum += e;
    }
    psum[cg * 64 + r] = lsum;
    __syncthreads();
    float inv = __builtin_amdgcn_rcpf(psum[r] + psum[64 + r] + psum[128 + r] + psum[192 + r]);

    float oacc[16] = {};
    for (int c = 0; c < 64; c++) {
        float pv = qs[r * 65 + c];
        #pragma unroll
        for (int j = 0; j < 16; j++)
            oacc[j] += pv * vs[c * 65 + cg * 16 + j];       // wave-uniform broadcast
    }
    unsigned short* dst = o + (long long)(rowBase + r) * 768 + h * 64 + cg * 16;
    #pragma unroll
    for (int j = 0; j < 16; j++) dst[j] = f2b(oacc[j] * inv);
}

extern "C" void kernel_launch(void* const* d_in, const int* in_sizes, int n_in,
                              void* d_out, int out_size, void* d_ws, size_t ws_size,
                              hipStream_t stream) {
    const float* input   = (const float*)d_in[0];
    const float* patch_w = (const float*)d_in[1];
    const float* patch_b = (const float*)d_in[2];
    const float* ln_g    = (const float*)d_in[3];
    const float* ln_b    = (const float*)d_in[4];
    const float* qkv_w   = (const float*)d_in[5];
    const float* qkv_b   = (const float*)d_in[6];
    const float* proj_w  = (const float*)d_in[7];
    const float* proj_b  = (const float*)d_in[8];
    const float* ff1_w   = (const float*)d_in[9];
    const float* ff1_b   = (const float*)d_in[10];
    const float* ff2_w   = (const float*)d_in[11];
    const float* ff2_b   = (const float*)d_in[12];
    float* out = (float*)d_out;

    const int MN = 16384;   // B*N tokens
    const int D = 768, F = 3072, TD = 2304;
    const int NY = MN / 256;  // 64 row-blocks (divisible by 8)

    // ---- workspace layout: 83,165,184 uint16 = 166.33 MB (proven to fit) ----
    unsigned short* wPatch = (unsigned short*)d_ws;            // (768,768)
    unsigned short* wQkvT  = wPatch + 589824;                  // (2304,768)
    unsigned short* wProjT = wQkvT + 1769472;                  // (768,768)
    unsigned short* wFf1T  = wProjT + 589824;                  // (3072,768)
    unsigned short* wFf2T  = wFf1T + 2359296;                  // (768,3072)
    unsigned short* bigBuf = wFf2T + 2359296;                  // 50331648: im2col -> h -> qkv -> h2
    unsigned short* xid    = bigBuf + 50331648;                // 12582912: identity -> x2 bf16
    unsigned short* t0     = xid + 12582912;                   // 12582912: y / o bf16
    // d_out (f32, 16384x768): xe (patch GEMM -> LN), then final output

    // ---- weight prep ----
    convert_bf16_kernel<<<(589824 + 255) / 256, 256, 0, stream>>>(patch_w, wPatch, 589824);
    transpose_to_bf16_kernel<<<(1769472 + 255) / 256, 256, 0, stream>>>(qkv_w, wQkvT, D, TD);
    transpose_to_bf16_kernel<<<(589824 + 255) / 256, 256, 0, stream>>>(proj_w, wProjT, D, D);
    transpose_to_bf16_kernel<<<(2359296 + 255) / 256, 256, 0, stream>>>(ff1_w, wFf1T, D, F);
    transpose_to_bf16_kernel<<<(2359296 + 255) / 256, 256, 0, stream>>>(ff2_w, wFf2T, F, D);

    // ---- pipeline ----
    im2col_kernel<<<(MN * 768) / 256, 256, 0, stream>>>(input, bigBuf);

    // G1: xe = im2col @ patch_w^T + patch_b  -> d_out (f32)
    gemm256_kernel<<<(D / 256) * NY, 512, 0, stream>>>(bigBuf, wPatch, patch_b, nullptr,
                                                       out, nullptr, MN, D, 768, 768, 0, 0);
    // LN + PE -> xid (bf16 identity + GEMM input)
    ln_pe_kernel<<<MN, 256, 0, stream>>>(out, ln_g, ln_b, xid);

    // FF#1: h = gelu(xid @ ff1 + b1) -> bigBuf (bf16, 100.7 MB)
    gemm256_kernel<<<(F / 256) * NY, 512, 0, stream>>>(xid, wFf1T, ff1_b, nullptr,
                                                       nullptr, bigBuf, MN, F, 768, 768, 1, 0);
    // y = h @ ff2 + b2 -> t0 (bf16)
    gemm256_kernel<<<(D / 256) * NY, 512, 0, stream>>>(bigBuf, wFf2T, ff2_b, nullptr,
                                                       nullptr, t0, MN, D, F, F, 0, 0);
    // qkv = y @ qkv_w + qkv_b -> bigBuf (bf16, 75.5 MB; h dead)
    gemm256_kernel<<<(TD / 256) * NY, 512, 0, stream>>>(t0, wQkvT, qkv_b, nullptr,
                                                        nullptr, bigBuf, MN, TD, 768, 768, 0, 0);
    // attention -> o (bf16) into t0
    attn_kernel<<<16 * 16 * 12, 256, 0, stream>>>(bigBuf, t0);

    // x2 = o @ proj + proj_b + identity(xid) -> xid (bf16; in-place per-element safe)
    gemm256_kernel<<<(D / 256) * NY, 512, 0, stream>>>(t0, wProjT, proj_b, xid,
                                                       nullptr, xid, MN, D, 768, 768, 0, 0);

    // FF#2: h2 = gelu(x2 @ ff1 + b1) -> bigBuf (qkv dead)
    gemm256_kernel<<<(F / 256) * NY, 512, 0, stream>>>(xid, wFf1T, ff1_b, nullptr,
                                                       nullptr, bigBuf, MN, F, 768, 768, 1, 0);
    // out = h2 @ ff2 + b2 + x2(bf16 resid)  (f32, final)
    gemm256_kernel<<<(D / 256) * NY, 512, 0, stream>>>(bigBuf, wFf2T, ff2_b, xid,
                                                       out, nullptr, MN, D, F, F, 0, 0);
}

// Round 3
// 932.221 us; speedup vs baseline: 1.0084x; 1.0084x over previous
//
#include <hip/hip_runtime.h>

typedef unsigned int uint;
typedef short bf16x8 __attribute__((ext_vector_type(8)));
typedef float f32x4 __attribute__((ext_vector_type(4)));

// ---------- bf16 helpers (bit-level, RNE) ----------
__device__ __forceinline__ unsigned short f2b(float f) {
    uint u = __builtin_bit_cast(uint, f);
    u += 0x7fffu + ((u >> 16) & 1u);
    return (unsigned short)(u >> 16);
}
__device__ __forceinline__ float b2f(unsigned short h) {
    uint u = ((uint)h) << 16;
    return __builtin_bit_cast(float, u);
}

// ---------- fast tanh-gelu ----------
__device__ __forceinline__ float fast_gelu(float v) {
    float s  = v * v;
    float t2 = __builtin_fmaf(0.044715f * s, v, v);     // v + 0.044715 v^3
    float e  = __expf(-1.5957691216f * t2);             // exp(-2*0.79788456*t2)
    return v * __builtin_amdgcn_rcpf(1.0f + e);
}

// ---------- async global->LDS, 16B per lane (wave-uniform LDS base + lane*16) ----------
__device__ __forceinline__ void gl_lds16(const unsigned short* g, unsigned short* l) {
    __builtin_amdgcn_global_load_lds(
        reinterpret_cast<const __attribute__((address_space(1))) unsigned int*>(
            reinterpret_cast<uintptr_t>(g)),
        reinterpret_cast<__attribute__((address_space(3))) unsigned int*>(
            reinterpret_cast<uintptr_t>(l)),
        16, 0, 0);
}

// ---------- weight prep ----------
__global__ __launch_bounds__(256) void convert_bf16_kernel(const float* __restrict__ src,
                                                           unsigned short* __restrict__ dst, int n) {
    int idx = blockIdx.x * 256 + threadIdx.x;
    if (idx < n) dst[idx] = f2b(src[idx]);
}

// src is (K, N) row-major; dst is (N, K) row-major (i.e. B^T), bf16.
__global__ __launch_bounds__(256) void transpose_to_bf16_kernel(const float* __restrict__ src,
                                                                unsigned short* __restrict__ dst,
                                                                int K, int N) {
    long long idx = (long long)blockIdx.x * 256 + threadIdx.x;
    if (idx >= (long long)K * N) return;
    int k = (int)(idx / N);
    int n = (int)(idx % N);
    dst[(long long)n * K + k] = f2b(src[idx]);
}

// ---------- im2col: input (B,C,H,W) -> A (16384, 768) bf16, k = c*256+p*16+q ----------
__global__ __launch_bounds__(256) void im2col_kernel(const float* __restrict__ in,
                                                     unsigned short* __restrict__ out) {
    long long idx = (long long)blockIdx.x * 256 + threadIdx.x; // < 16384*768
    int k = (int)(idx % 768);
    int n = (int)(idx / 768);
    int b = n >> 10, t = n & 1023;
    int hp = t >> 5, wp = t & 31;
    int c = k >> 8, rm = k & 255;
    int p = rm >> 4, q = rm & 15;
    long long src = (((long long)(b * 3 + c) * 512) + hp * 16 + p) * 512 + wp * 16 + q;
    out[idx] = f2b(in[src]);
}

// ---------- LayerNorm + sinusoidal PE -> bf16 ----------
__global__ __launch_bounds__(256) void ln_pe_kernel(const float* __restrict__ xe,
                                                    const float* __restrict__ g,
                                                    const float* __restrict__ bb,
                                                    unsigned short* __restrict__ xb) {
    int row = blockIdx.x;            // 0..16383
    int pos = row & 1023;
    const float* xr = xe + (long long)row * 768;
    float v0 = xr[threadIdx.x];
    float v1 = xr[threadIdx.x + 256];
    float v2 = xr[threadIdx.x + 512];
    float s = v0 + v1 + v2;
    float sq = v0 * v0 + v1 * v1 + v2 * v2;
    for (int o = 32; o > 0; o >>= 1) {
        s  += __shfl_down(s, o, 64);
        sq += __shfl_down(sq, o, 64);
    }
    __shared__ float ps[4], pq[4];
    int w = threadIdx.x >> 6, lane = threadIdx.x & 63;
    if (lane == 0) { ps[w] = s; pq[w] = sq; }
    __syncthreads();
    float ts = ps[0] + ps[1] + ps[2] + ps[3];
    float tq = pq[0] + pq[1] + pq[2] + pq[3];
    float mean = ts * (1.0f / 768.0f);
    float var  = tq * (1.0f / 768.0f) - mean * mean;
    float inv  = rsqrtf(var + 1e-5f);
    #pragma unroll
    for (int dd = 0; dd < 3; dd++) {
        int d = threadIdx.x + dd * 256;
        float val = (dd == 0) ? v0 : (dd == 1) ? v1 : v2;
        float y = (val - mean) * inv * g[d] + bb[d];
        float freq = __expf(-(float)(d & ~1) * (9.210340371976184f / 768.0f));
        float ang = (float)pos * freq;
        y += (d & 1) ? cosf(ang) : sinf(ang);
        xb[(long long)row * 768 + d] = f2b(y);
    }
}

// ---------- 256x256 bf16 MFMA GEMM, BK=64, 4-phase counted-vmcnt/lgkmcnt pipeline ----------
// ALL fragment LDS loads are inline-asm ds_read_b128 (invisible to SIInsertWaitcnts) so
// the compiler cannot insert vmcnt(0) drains before them; the only waitcnts in the K-loop
// are hand-counted. Fragments are read ONE PHASE AHEAD with counted lgkm (DS ops retire
// in order among themselves):
//   pre : read afA(A0,tile0) + bfr0(B0,tile0)                 [12 out]
//   p0  : read bfr1(B1)  | stage B0(s+1,bn) | BAR lgkm(4)  -> MFMA q00(afA,bfr0)
//   p1  : read afB(A1)   | stage A0(s+2,b)  | BAR lgkm(8)  -> MFMA q01(afA,bfr1)
//   p2  :                | stage B1(s+2,b)  | BAR lgkm(0)  -> MFMA q11(afB,bfr1)
//         vmcnt(4)  (retires exactly tile s+1's 8 staging loads)  BAR
//   p3  : toggle bases->bn; read afA,bfr0 (tile s+1) ; MFMA q10(afB,bfr0) ;
//         stage A1(s+2,b) ; BAR
// vmem FIFO: prologue 14 loads, vmcnt(6) retires tile0; steady +8/iter, vmcnt(4)
// retires one full tile. WAR hazards all barrier-separated (verified per slot).
// LDS slot (row,c8) holds global (row, c8^(row&7)); swizzle on the fetch side.
// sched_barrier(0) fences pin the MFMA clusters (rule 18: hipcc otherwise migrates
// register-only MFMAs across volatile-asm waitcnts/barriers).
__global__ __launch_bounds__(512) void gemm256_kernel(const unsigned short* __restrict__ A,
                                                      const unsigned short* __restrict__ BT,
                                                      const float* __restrict__ bias,
                                                      const unsigned short* __restrict__ residB,
                                                      float* __restrict__ outF,
                                                      unsigned short* __restrict__ outB,
                                                      int M, int N, int K, int ldb,
                                                      int epi, int accumF) {
    __shared__ __align__(16) unsigned short As[2][256 * 64];   // 64 KB
    __shared__ __align__(16) unsigned short Bs[2][256 * 64];   // 64 KB

    // ---- XCD swizzle: id = 8*s + xcd; requires (M/256) % 8 == 0 (holds: 64)
    const int nX = N >> 8;                    // N/256
    int id = blockIdx.x;
    int xcd = id & 7;
    int sq_ = id >> 3;
    int bx = sq_ % nX;
    int by = (sq_ / nX) * 8 + xcd;
    const int m0 = by * 256, n0 = bx * 256;

    const int tid = threadIdx.x;
    const int w = tid >> 6, lane = tid & 63;
    const int wr = w >> 2, wc = w & 3;               // 2x4 wave grid
    const int quad = lane >> 4, l15 = lane & 15;
    const int swz = l15 & 7;                         // fragment-row swizzle key

    // ---- staging addressing: thread t -> LDS 16B-unit t (wave-uniform base + lane*16)
    const int row0 = tid >> 3;                       // 0..63
    const int c8   = tid & 7;
    const int gc8  = c8 ^ (row0 & 7);                // (row0+64)&7 == row0&7
    const unsigned short* Ag = A  + (long long)(m0 + row0) * K   + gc8 * 8;
    const unsigned short* Bg = BT + (long long)(n0 + row0) * ldb + gc8 * 8;
    unsigned short* Ad = &As[0][0] + row0 * 64 + c8 * 8;
    unsigned short* Bd = &Bs[0][0] + row0 * 64 + c8 * 8;
    const long long aK64 = (long long)64 * K,  aK128 = (long long)128 * K;
    const long long bL64 = (long long)64 * ldb, bL128 = (long long)128 * ldb;

#define STAGE_A(bsel, h, ks) { \
    const unsigned short* s_ = Ag + (h) * aK128 + (ks); \
    unsigned short* d_ = Ad + (bsel) * 16384 + (h) * 8192; \
    gl_lds16(s_, d_); gl_lds16(s_ + aK64, d_ + 4096); }
#define STAGE_B(bsel, h, ks) { \
    const unsigned short* s_ = Bg + (h) * bL128 + (ks); \
    unsigned short* d_ = Bd + (bsel) * 16384 + (h) * 8192; \
    gl_lds16(s_, d_); gl_lds16(s_ + bL64, d_ + 4096); }

    // ---- fragment LDS byte addresses (buffer 0); per-iter XOR 0x8000 toggles buffer.
    // (Truncating the generic pointer keeps the LDS byte offset: aperture is in hi32.)
    // A frag (qm,mf,h): aH<h> + qm*16384 + mf*2048 ; B frag (qn,nf,h): bH<h> + qn*16384 + nf*2048
    unsigned asB = (unsigned)(uintptr_t)(&As[0][0]);
    unsigned bsB = (unsigned)(uintptr_t)(&Bs[0][0]);
    unsigned aH0 = asB + (unsigned)((wr * 64 + l15) * 128 + ((quad ^ swz) * 16));
    unsigned aH1 = asB + (unsigned)((wr * 64 + l15) * 128 + (((4 + quad) ^ swz) * 16));
    unsigned bH0 = bsB + (unsigned)((wc * 32 + l15) * 128 + ((quad ^ swz) * 16));
    unsigned bH1 = bsB + (unsigned)((wc * 32 + l15) * 128 + (((4 + quad) ^ swz) * 16));

    bf16x8 afA[4][2], afB[4][2], bfr0[2][2], bfr1[2][2];
    f32x4 acc[2][2][4][2] = {};

#define DSR(dst, addr, IMM) \
    asm volatile("ds_read_b128 %0, %1 offset:%2" : "=&v"(dst) : "v"(addr), "i"(IMM))

#define R_A0() { DSR(afA[0][0], aH0, 0);     DSR(afA[1][0], aH0, 2048); \
                 DSR(afA[2][0], aH0, 4096);  DSR(afA[3][0], aH0, 6144); \
                 DSR(afA[0][1], aH1, 0);     DSR(afA[1][1], aH1, 2048); \
                 DSR(afA[2][1], aH1, 4096);  DSR(afA[3][1], aH1, 6144); }
#define R_A1() { DSR(afB[0][0], aH0, 16384); DSR(afB[1][0], aH0, 18432); \
                 DSR(afB[2][0], aH0, 20480); DSR(afB[3][0], aH0, 22528); \
                 DSR(afB[0][1], aH1, 16384); DSR(afB[1][1], aH1, 18432); \
                 DSR(afB[2][1], aH1, 20480); DSR(afB[3][1], aH1, 22528); }
#define R_B0() { DSR(bfr0[0][0], bH0, 0);     DSR(bfr0[1][0], bH0, 2048); \
                 DSR(bfr0[0][1], bH1, 0);     DSR(bfr0[1][1], bH1, 2048); }
#define R_B1() { DSR(bfr1[0][0], bH0, 16384); DSR(bfr1[1][0], bH0, 18432); \
                 DSR(bfr1[0][1], bH1, 16384); DSR(bfr1[1][1], bH1, 18432); }

#define MFMA16(AF, BF, qm, qn) { \
    __builtin_amdgcn_sched_barrier(0); \
    __builtin_amdgcn_s_setprio(1); \
    _Pragma("unroll") for (int mf_ = 0; mf_ < 4; mf_++) \
    _Pragma("unroll") for (int nf_ = 0; nf_ < 2; nf_++) { \
      acc[qm][qn][mf_][nf_] = __builtin_amdgcn_mfma_f32_16x16x32_bf16(AF[mf_][0], BF[nf_][0], acc[qm][qn][mf_][nf_], 0, 0, 0); \
      acc[qm][qn][mf_][nf_] = __builtin_amdgcn_mfma_f32_16x16x32_bf16(AF[mf_][1], BF[nf_][1], acc[qm][qn][mf_][nf_], 0, 0, 0); \
    } \
    __builtin_amdgcn_s_setprio(0); \
    __builtin_amdgcn_sched_barrier(0); }

#define BAR() { asm volatile("" ::: "memory"); __builtin_amdgcn_s_barrier(); asm volatile("" ::: "memory"); }
#define WAITL(n) { asm volatile("s_waitcnt lgkmcnt(" #n ")" ::: "memory"); __builtin_amdgcn_sched_barrier(0); }
#define WAITV(n) { asm volatile("s_waitcnt vmcnt(" #n ")" ::: "memory"); }

    const int NT = K >> 6;                    // K-tiles (>= 2 for all call sites)

    // ---- prologue: tile0 fully + {A0,B1,A1}(1) staged; vmcnt(6) retires tile0 exactly
    STAGE_B(0, 0, 0);
    STAGE_A(0, 0, 0);
    STAGE_B(0, 1, 0);
    STAGE_A(0, 1, 0);
    STAGE_A(1, 0, 64);
    STAGE_B(1, 1, 64);
    STAGE_A(1, 1, 64);
    WAITV(6);
    BAR();
    R_A0();                                   // tile0 A0 frags   (8 reads)
    R_B0();                                   // tile0 B0 frags   (4 reads)

    for (int s = 0; s < NT; s++) {
        const int b = s & 1, bn = b ^ 1;
        const int ks1 = (s + 1 < NT) ? (s + 1) * 64 : 0;   // dummy loads keep FIFO exact
        const int ks2 = (s + 2 < NT) ? (s + 2) * 64 : 0;

        // ---- p0: prefetch B1 frags; MFMA q00
        R_B1();                               // +4  (out: 16)
        STAGE_B(bn, 0, ks1);
        BAR();
        WAITL(4);                             // retire afA + bfr0 (12)
        MFMA16(afA, bfr0, 0, 0);
        BAR();
        // ---- p1: prefetch A1 frags; MFMA q01
        R_A1();                               // +8  (out: 12)
        STAGE_A(b, 0, ks2);
        BAR();
        WAITL(8);                             // retire bfr1 (4)
        MFMA16(afA, bfr1, 0, 1);
        BAR();
        // ---- p2: MFMA q11; then counted vmem wait gating next-tile frag reads
        STAGE_B(b, 1, ks2);
        BAR();
        WAITL(0);                             // retire afB (8)
        MFMA16(afB, bfr1, 1, 1);
        WAITV(4);                             // retires exactly tile s+1's 8 loads
        BAR();
        // ---- p3: next-tile A0/B0 frags from buffer bn; MFMA q10
        aH0 ^= 32768u; aH1 ^= 32768u; bH0 ^= 32768u; bH1 ^= 32768u;
        R_A0();                               // tile s+1 A0 (8)
        MFMA16(afB, bfr0, 1, 0);
        R_B0();                               // tile s+1 B0 (4)  (reg WAR only)
        STAGE_A(b, 1, ks2);
        BAR();
    }
    asm volatile("s_waitcnt vmcnt(0) lgkmcnt(0)" ::: "memory");  // drain tail dummies
    __builtin_amdgcn_sched_barrier(0);

    // ---- epilogue: v = acc (+ bias); epi==1 -> gelu; accumF -> +outF; residB -> +resid
    const int r0 = quad * 4;
    #pragma unroll
    for (int qm = 0; qm < 2; qm++)
    #pragma unroll
    for (int qn = 0; qn < 2; qn++)
    #pragma unroll
    for (int mf = 0; mf < 4; mf++)
    #pragma unroll
    for (int nf = 0; nf < 2; nf++) {
        int gn = n0 + qn * 128 + wc * 32 + nf * 16 + l15;
        float bv = bias ? bias[gn] : 0.0f;
        #pragma unroll
        for (int r = 0; r < 4; r++) {
            int gm = m0 + qm * 128 + wr * 64 + mf * 16 + r0 + r;
            float v = acc[qm][qn][mf][nf][r] + bv;
            if (epi == 1) v = fast_gelu(v);
            long long off = (long long)gm * N + gn;
            if (accumF) v += outF[off];
            if (residB) v += b2f(residB[off]);
            if (outF) outF[off] = v;
            if (outB) outB[off] = f2b(v);
        }
    }
#undef STAGE_A
#undef STAGE_B
#undef DSR
#undef R_A0
#undef R_A1
#undef R_B0
#undef R_B1
#undef MFMA16
#undef BAR
#undef WAITL
#undef WAITV
}

// ---------- windowed attention: one block per (b, window, head), 52 KB LDS ----------
__global__ __launch_bounds__(256) void attn_kernel(const unsigned short* __restrict__ qkv,
                                                   unsigned short* __restrict__ o) {
    __shared__ float qs[64 * 65], ks[64 * 65], vs[64 * 65];  // qs reused for probs
    __shared__ float pmax[4 * 64], psum[4 * 64];
    int blk = blockIdx.x;                 // b*16*12 + w*12 + h
    int h = blk % 12;
    int bw = blk / 12;
    int wi = bw % 16, b = bw / 16;
    int rowBase = b * 1024 + wi * 64;
    int tid = threadIdx.x;

    int lr = tid >> 2, c0 = (tid & 3) * 16;
    const unsigned short* src = qkv + (long long)(rowBase + lr) * 2304 + h * 64 + c0;
    #pragma unroll
    for (int j = 0; j < 16; j++) {
        qs[lr * 65 + c0 + j] = b2f(src[j]);
        ks[lr * 65 + c0 + j] = b2f(src[768 + j]);
        vs[lr * 65 + c0 + j] = b2f(src[1536 + j]);
    }
    __syncthreads();

    int r = tid & 63, cg = tid >> 6;
    float svals[16] = {};
    for (int kk = 0; kk < 64; kk++) {
        float qv = qs[r * 65 + kk];                    // per-lane, 2-way bank alias (free)
        #pragma unroll
        for (int j = 0; j < 16; j++)
            svals[j] += qv * ks[(cg * 16 + j) * 65 + kk];   // wave-uniform broadcast
    }
    float smax = -1e30f;
    #pragma unroll
    for (int j = 0; j < 16; j++) {
        svals[j] *= 0.125f;
        smax = fmaxf(smax, svals[j]);
    }
    pmax[cg * 64 + r] = smax;
    __syncthreads();   // all qs(Q) reads done; qs reusable as prob buffer
    float m = fmaxf(fmaxf(pmax[r], pmax[64 + r]), fmaxf(pmax[128 + r], pmax[192 + r]));
    float lsum = 0.0f;
    #pragma unroll
    for (int j = 0; j < 16; j++) {
        float e = __expf(svals[j] - m);
        qs[r * 65 + cg * 16 + j] = e;
        lsum += e;
    }
    psum[cg * 64 + r] = lsum;
    __syncthreads();
    float inv = __builtin_amdgcn_rcpf(psum[r] + psum[64 + r] + psum[128 + r] + psum[192 + r]);

    float oacc[16] = {};
    for (int c = 0; c < 64; c++) {
        float pv = qs[r * 65 + c];
        #pragma unroll
        for (int j = 0; j < 16; j++)
            oacc[j] += pv * vs[c * 65 + cg * 16 + j];       // wave-uniform broadcast
    }
    unsigned short* dst = o + (long long)(rowBase + r) * 768 + h * 64 + cg * 16;
    #pragma unroll
    for (int j = 0; j < 16; j++) dst[j] = f2b(oacc[j] * inv);
}

extern "C" void kernel_launch(void* const* d_in, const int* in_sizes, int n_in,
                              void* d_out, int out_size, void* d_ws, size_t ws_size,
                              hipStream_t stream) {
    const float* input   = (const float*)d_in[0];
    const float* patch_w = (const float*)d_in[1];
    const float* patch_b = (const float*)d_in[2];
    const float* ln_g    = (const float*)d_in[3];
    const float* ln_b    = (const float*)d_in[4];
    const float* qkv_w   = (const float*)d_in[5];
    const float* qkv_b   = (const float*)d_in[6];
    const float* proj_w  = (const float*)d_in[7];
    const float* proj_b  = (const float*)d_in[8];
    const float* ff1_w   = (const float*)d_in[9];
    const float* ff1_b   = (const float*)d_in[10];
    const float* ff2_w   = (const float*)d_in[11];
    const float* ff2_b   = (const float*)d_in[12];
    float* out = (float*)d_out;

    const int MN = 16384;   // B*N tokens
    const int D = 768, F = 3072, TD = 2304;
    const int NY = MN / 256;  // 64 row-blocks (divisible by 8)

    // ---- workspace layout: 83,165,184 uint16 = 166.33 MB (proven to fit) ----
    unsigned short* wPatch = (unsigned short*)d_ws;            // (768,768)
    unsigned short* wQkvT  = wPatch + 589824;                  // (2304,768)
    unsigned short* wProjT = wQkvT + 1769472;                  // (768,768)
    unsigned short* wFf1T  = wProjT + 589824;                  // (3072,768)
    unsigned short* wFf2T  = wFf1T + 2359296;                  // (768,3072)
    unsigned short* bigBuf = wFf2T + 2359296;                  // 50331648: im2col -> h -> qkv -> h2
    unsigned short* xid    = bigBuf + 50331648;                // 12582912: identity -> x2 bf16
    unsigned short* t0     = xid + 12582912;                   // 12582912: y / o bf16
    // d_out (f32, 16384x768): xe (patch GEMM -> LN), then final output

    // ---- weight prep ----
    convert_bf16_kernel<<<(589824 + 255) / 256, 256, 0, stream>>>(patch_w, wPatch, 589824);
    transpose_to_bf16_kernel<<<(1769472 + 255) / 256, 256, 0, stream>>>(qkv_w, wQkvT, D, TD);
    transpose_to_bf16_kernel<<<(589824 + 255) / 256, 256, 0, stream>>>(proj_w, wProjT, D, D);
    transpose_to_bf16_kernel<<<(2359296 + 255) / 256, 256, 0, stream>>>(ff1_w, wFf1T, D, F);
    transpose_to_bf16_kernel<<<(2359296 + 255) / 256, 256, 0, stream>>>(ff2_w, wFf2T, F, D);

    // ---- pipeline ----
    im2col_kernel<<<(MN * 768) / 256, 256, 0, stream>>>(input, bigBuf);

    // G1: xe = im2col @ patch_w^T + patch_b  -> d_out (f32)
    gemm256_kernel<<<(D / 256) * NY, 512, 0, stream>>>(bigBuf, wPatch, patch_b, nullptr,
                                                       out, nullptr, MN, D, 768, 768, 0, 0);
    // LN + PE -> xid (bf16 identity + GEMM input)
    ln_pe_kernel<<<MN, 256, 0, stream>>>(out, ln_g, ln_b, xid);

    // FF#1: h = gelu(xid @ ff1 + b1) -> bigBuf (bf16, 100.7 MB)
    gemm256_kernel<<<(F / 256) * NY, 512, 0, stream>>>(xid, wFf1T, ff1_b, nullptr,
                                                       nullptr, bigBuf, MN, F, 768, 768, 1, 0);
    // y = h @ ff2 + b2 -> t0 (bf16)
    gemm256_kernel<<<(D / 256) * NY, 512, 0, stream>>>(bigBuf, wFf2T, ff2_b, nullptr,
                                                       nullptr, t0, MN, D, F, F, 0, 0);
    // qkv = y @ qkv_w + qkv_b -> bigBuf (bf16, 75.5 MB; h dead)
    gemm256_kernel<<<(TD / 256) * NY, 512, 0, stream>>>(t0, wQkvT, qkv_b, nullptr,
                                                        nullptr, bigBuf, MN, TD, 768, 768, 0, 0);
    // attention -> o (bf16) into t0
    attn_kernel<<<16 * 16 * 12, 256, 0, stream>>>(bigBuf, t0);

    // x2 = o @ proj + proj_b + identity(xid) -> xid (bf16; in-place per-element safe)
    gemm256_kernel<<<(D / 256) * NY, 512, 0, stream>>>(t0, wProjT, proj_b, xid,
                                                       nullptr, xid, MN, D, 768, 768, 0, 0);

    // FF#2: h2 = gelu(x2 @ ff1 + b1) -> bigBuf (qkv dead)
    gemm256_kernel<<<(F / 256) * NY, 512, 0, stream>>>(xid, wFf1T, ff1_b, nullptr,
                                                       nullptr, bigBuf, MN, F, 768, 768, 1, 0);
    // out = h2 @ ff2 + b2 + x2(bf16 resid)  (f32, final)
    gemm256_kernel<<<(D / 256) * NY, 512, 0, stream>>>(bigBuf, wFf2T, ff2_b, xid,
                                                       out, nullptr, MN, D, F, F, 0, 0);
}